// Round 16
// baseline (120922.339 us; speedup 1.0000x reference)
//
#include <hip/hip_runtime.h>
#include <hip/hip_bf16.h>

#define NN 4096
#define NFEAT 256
#define NHID1 64
#define NHID2 32
#define NCLASS 8
#define NHEADS 4
#define NADJ 2
#define CAP 128
#define NB 1024  // 4 blocks/CU co-resident (24KB LDS, ~76 VGPR) -> barrier safe

// f32 -> bf16 round-to-nearest-even
__device__ __forceinline__ unsigned short f2bf(float v) {
  unsigned int x = __float_as_uint(v);
  return (unsigned short)((x + 0x7fffu + ((x >> 16) & 1u)) >> 16);
}

// Device-wide barrier. Monotonic arrival counter (no reset race): barrier k
// is complete when cnt >= k*NB.
// R14 lesson: acquire-POLLING emits buffer_inv per poll -> L2-inv storm.
// R15 lesson: relaxed LOADS read the poller's own non-coherent XCD L2 ->
// never see the remote write -> deadlock. Fix: poll with an atomic RMW
// (fetch_add of 0) — RMWs execute at the coherence point (LLC), no cache
// side-effects. One release fence on entry, one acquire fence on exit.
// Escape hatch: cap the spin (~21ms) so a co-residency failure fails fast
// (wrong answer) instead of hanging the harness.
__device__ __forceinline__ void gbar(int* cnt, int epoch) {
  __syncthreads();
  if (threadIdx.x == 0) {
    __builtin_amdgcn_fence(__ATOMIC_RELEASE, "agent");  // wbl2 once
    __hip_atomic_fetch_add(cnt, 1, __ATOMIC_RELAXED, __HIP_MEMORY_SCOPE_AGENT);
    int it = 0;
    while (__hip_atomic_fetch_add(cnt, 0, __ATOMIC_RELAXED,
                                  __HIP_MEMORY_SCOPE_AGENT) < epoch * NB) {
      __builtin_amdgcn_s_sleep(32);  // ~2k cycles between polls
      if (++it > 25000) break;       // fail-fast escape (never in normal runs)
    }
    __builtin_amdgcn_fence(__ATOMIC_ACQUIRE, "agent");  // inv once
  }
  __syncthreads();
}

// ---------------------------------------------------------------------------
// Register-blocked GEMM tile (R9 body): C = act(A@B + bias); optional bf16
// output and fused attention coefs. smem provided by caller.
template <int KDIM, int NDIM, int RPTY, int ACT, int COEF, int OBF16>
__device__ __forceinline__ void gemm_dev(
    const float* __restrict__ A, const float* __restrict__ B,
    const float* __restrict__ bias, void* __restrict__ C,
    const float* __restrict__ ag, float* __restrict__ fsrc,
    float* __restrict__ fdst, const int row0b, float* __restrict__ sA,
    float* __restrict__ sB) {
  constexpr int KT = 32;
  constexpr int TX = NDIM / 4;
  constexpr int TY = 256 / TX;
  constexpr int BR = TY * RPTY;
  constexpr int LDA = BR + 4;
  constexpr int LDB = NDIM + 4;
  const int tid = threadIdx.x;
  const int tx = tid % TX, ty = tid / TX;
  const int c0 = tx * 4;
  float acc[RPTY][4];
#pragma unroll
  for (int i = 0; i < RPTY; ++i)
#pragma unroll
    for (int j = 0; j < 4; ++j) acc[i][j] = 0.f;

  for (int kt = 0; kt < KDIM; kt += KT) {
    __syncthreads();
    for (int i = tid; i < BR * (KT / 4); i += 256) {
      const int r = i / (KT / 4), e = i % (KT / 4);
      const float4 v = *(const float4*)(A + (size_t)(row0b + r) * KDIM + kt + e * 4);
      sA[(e * 4 + 0) * LDA + r] = v.x;
      sA[(e * 4 + 1) * LDA + r] = v.y;
      sA[(e * 4 + 2) * LDA + r] = v.z;
      sA[(e * 4 + 3) * LDA + r] = v.w;
    }
    for (int i = tid; i < KT * (NDIM / 4); i += 256) {
      const int k = i / (NDIM / 4), cc = i % (NDIM / 4);
      *(float4*)&sB[k * LDB + cc * 4] = *(const float4*)(B + (size_t)(kt + k) * NDIM + cc * 4);
    }
    __syncthreads();
#pragma unroll
    for (int k = 0; k < KT; ++k) {
      float a4[RPTY];
      if constexpr (RPTY == 4) {
        const float4 t = *(const float4*)&sA[k * LDA + ty * 4];
        a4[0] = t.x; a4[1] = t.y; a4[2] = t.z; a4[3] = t.w;
      } else {
        const float2 t = *(const float2*)&sA[k * LDA + ty * 2];
        a4[0] = t.x; a4[1] = t.y;
      }
      const float4 bv = *(const float4*)&sB[k * LDB + c0];
      const float b4[4] = {bv.x, bv.y, bv.z, bv.w};
#pragma unroll
      for (int i = 0; i < RPTY; ++i)
#pragma unroll
        for (int j = 0; j < 4; ++j) acc[i][j] += a4[i] * b4[j];
    }
  }
  float b4[4] = {0.f, 0.f, 0.f, 0.f};
  if (bias) {
    const float4 bb = *(const float4*)&bias[c0];
    b4[0] = bb.x; b4[1] = bb.y; b4[2] = bb.z; b4[3] = bb.w;
  }
#pragma unroll
  for (int i = 0; i < RPTY; ++i) {
    const int row = row0b + ty * RPTY + i;
    float v[4];
#pragma unroll
    for (int j = 0; j < 4; ++j) {
      v[j] = acc[i][j] + b4[j];
      if (ACT == 1) v[j] = v[j] > 0.f ? v[j] : (__expf(v[j]) - 1.f);  // elu
    }
    if constexpr (OBF16) {
      ushort4 o;
      o.x = f2bf(v[0]); o.y = f2bf(v[1]); o.z = f2bf(v[2]); o.w = f2bf(v[3]);
      *(ushort4*)((unsigned short*)C + (size_t)row * NDIM + c0) = o;
    } else {
      float4 o;
      o.x = v[0]; o.y = v[1]; o.z = v[2]; o.w = v[3];
      *(float4*)((float*)C + (size_t)row * NDIM + c0) = o;
    }
  }
  if constexpr (COEF) {
    float aS[4], aD[4];
#pragma unroll
    for (int j = 0; j < 4; ++j) { aS[j] = ag[c0 + j]; aD[j] = ag[NDIM + c0 + j]; }
#pragma unroll
    for (int i = 0; i < RPTY; ++i) {
      float s = 0.f, d = 0.f;
#pragma unroll
      for (int j = 0; j < 4; ++j) { s += acc[i][j] * aS[j]; d += acc[i][j] * aD[j]; }
#pragma unroll
      for (int off = TX / 2; off; off >>= 1) {
        s += __shfl_xor(s, off);
        d += __shfl_xor(d, off);
      }
      if (tx == 0) {
        const int row = row0b + ty * RPTY + i;
        fsrc[row] = s;
        fdst[row] = d;
      }
    }
  }
}

// ---------------------------------------------------------------------------
// Sparse softmax + bf16 gather + elu for one (g,h,n) per wave (R9 body).
template <int O>
__device__ __forceinline__ void agg_task(
    int g, int h, int n, const unsigned short* __restrict__ Wh,
    const float* __restrict__ fsrc, const float* __restrict__ fdst,
    const int* __restrict__ eidx, const int* __restrict__ ecnt,
    float* __restrict__ Hout, int lane, float* __restrict__ wgtrow,
    int* __restrict__ midxrow) {
  constexpr int CPL = O / 8;     // lanes per edge row
  constexpr int EPW = 64 / CPL;  // edges in parallel
  const int gh = g * NHEADS + h;
  const int cnt = ecnt[(size_t)g * NN + n];
  const int* ei = eidx + (size_t)(g * NN + n) * CAP;
  const float fs = fsrc[(size_t)gh * NN + n];
  const float* fd = fdst + (size_t)gh * NN;
  float mx = -3.4e38f;
  for (int j = lane; j < cnt; j += 64) {
    const int m = ei[j];
    float e = fs + fd[m];
    e = e > 0.f ? e : 0.2f * e;  // leaky relu alpha=0.2
    midxrow[j] = m;
    wgtrow[j] = e;
    mx = fmaxf(mx, e);
  }
  for (int off = 32; off; off >>= 1) mx = fmaxf(mx, __shfl_xor(mx, off));
  float sm = 0.f;
  for (int j = lane; j < cnt; j += 64) {
    const float w = __expf(wgtrow[j] - mx);
    wgtrow[j] = w;
    sm += w;
  }
  for (int off = 32; off; off >>= 1) sm += __shfl_xor(sm, off);
  const unsigned short* WhH = Wh + (size_t)gh * NN * O;
  const int sub = lane / CPL;
  const int c8 = (lane % CPL) * 8;
  float A0[8] = {0, 0, 0, 0, 0, 0, 0, 0};
  float A1[8] = {0, 0, 0, 0, 0, 0, 0, 0};
#define GATB(ACC, JJ)                                                          \
  {                                                                            \
    const float w_ = wgtrow[JJ];                                               \
    const uint4 v_ = *(const uint4*)(WhH + (size_t)midxrow[JJ] * O + c8);      \
    ACC[0] += w_ * __uint_as_float(v_.x << 16);                                \
    ACC[1] += w_ * __uint_as_float(v_.x & 0xffff0000u);                        \
    ACC[2] += w_ * __uint_as_float(v_.y << 16);                                \
    ACC[3] += w_ * __uint_as_float(v_.y & 0xffff0000u);                        \
    ACC[4] += w_ * __uint_as_float(v_.z << 16);                                \
    ACC[5] += w_ * __uint_as_float(v_.z & 0xffff0000u);                        \
    ACC[6] += w_ * __uint_as_float(v_.w << 16);                                \
    ACC[7] += w_ * __uint_as_float(v_.w & 0xffff0000u);                        \
  }
  int j = sub;
  for (; j + EPW < cnt; j += 2 * EPW) {
    GATB(A0, j);
    GATB(A1, j + EPW);
  }
  for (; j < cnt; j += EPW) GATB(A0, j);
#undef GATB
#pragma unroll
  for (int q = 0; q < 8; ++q) A0[q] += A1[q];
#pragma unroll
  for (int off = CPL; off < 64; off <<= 1)
#pragma unroll
    for (int q = 0; q < 8; ++q) A0[q] += __shfl_xor(A0[q], off);
  if (lane < CPL) {
    const float inv = 1.f / sm;
    float o[8];
#pragma unroll
    for (int q = 0; q < 8; ++q) {
      o[q] = A0[q] * inv;
      o[q] = o[q] > 0.f ? o[q] : (__expf(o[q]) - 1.f);  // elu
    }
    float* dst = Hout + (size_t)g * NN * (NHEADS * O) + (size_t)n * (NHEADS * O) +
                 h * O + lane * 8;
    float4 o0, o1;
    o0.x = o[0]; o0.y = o[1]; o0.z = o[2]; o0.w = o[3];
    o1.x = o[4]; o1.y = o[5]; o1.z = o[6]; o1.w = o[7];
    *(float4*)dst = o0;
    *(float4*)(dst + 4) = o1;
  }
}

// ---------------------------------------------------------------------------
// Persistent mega-kernel: 6 stages, 5 device-wide barriers.
__global__ __launch_bounds__(256) void mega(
    const float* __restrict__ x, const float* __restrict__ adj,
    const float* __restrict__ W1, const float* __restrict__ a1,
    const float* __restrict__ W2, const float* __restrict__ a2,
    const float* __restrict__ Wi1, const float* __restrict__ bi1,
    const float* __restrict__ Wi2, const float* __restrict__ bi2,
    const float* __restrict__ Wf, const float* __restrict__ bfv,
    float* __restrict__ out, int* __restrict__ barCnt,
    int* __restrict__ eidx, int* __restrict__ ecnt,
    unsigned short* __restrict__ Wh1, float* __restrict__ fs1,
    float* __restrict__ fd1, float* __restrict__ h1, float* __restrict__ x1,
    unsigned short* __restrict__ Wh2, float* __restrict__ fs2,
    float* __restrict__ fd2, float* __restrict__ h2) {
  __shared__ __align__(16) float smem[6144];  // 24 KB union across stages
  const int tid = threadIdx.x;
  const int wave = tid >> 6;
  const int lane = tid & 63;
  const int bid = blockIdx.x;

  // ===== S1: L1 GAT GEMM (+coef1, bf16 Wh1) on blocks 0..511; edge build
  // spread over all blocks (2 units of 4 rows each).
  for (int t = bid; t < 512; t += NB) {
    const int tile = t % (NN / 64);
    const int h = (t / (NN / 64)) % NHEADS;
    const int g = t / ((NN / 64) * NHEADS);
    const int gh = g * NHEADS + h;
    gemm_dev<NFEAT, NHID1, 4, 0, 1, 1>(
        x, W1 + (size_t)gh * NFEAT * NHID1, nullptr,
        Wh1 + (size_t)gh * NN * NHID1, a1 + (size_t)gh * 2 * NHID1,
        fs1 + (size_t)gh * NN, fd1 + (size_t)gh * NN, tile * 64, smem,
        smem + 32 * 68);
  }
  for (int u = bid; u < NADJ * NN / 4; u += NB) {
    const int r = u * 4 + wave;  // g*NN + n
    const float4* row = (const float4*)(adj + (size_t)r * NN);
    int* outp = eidx + (size_t)r * CAP;
    int base = 0;
    for (int c = 0; c < NN; c += 256) {
      const float4 v = row[(c >> 2) + lane];
      const int j0 = c + lane * 4;
      const float vt[4] = {v.x, v.y, v.z, v.w};
#pragma unroll
      for (int t = 0; t < 4; ++t) {
        const bool hit = vt[t] > 0.f;
        const unsigned long long m = __ballot(hit);
        if (hit) {
          const int pos = base + __popcll(m & ((1ull << lane) - 1ull));
          if (pos < CAP) outp[pos] = j0 + t;
        }
        base += __popcll(m);
      }
    }
    if (lane == 0) ecnt[r] = base < CAP ? base : CAP;
  }
  gbar(barCnt, 1);

  // ===== S2: L1 aggregate — one (g,h,n) per wave, 8 tasks/wave.
  {
    float* wgtrow = smem + wave * CAP;
    int* midxrow = (int*)(smem + 4 * CAP) + wave * CAP;
    const int gw = bid * 4 + wave;
    for (int tsk = gw; tsk < NADJ * NHEADS * NN; tsk += NB * 4) {
      const int n = tsk & (NN - 1);
      const int h = (tsk >> 12) & (NHEADS - 1);
      const int g = tsk >> 14;
      agg_task<NHID1>(g, h, n, Wh1, fs1, fd1, eidx, ecnt, h1, lane, wgtrow, midxrow);
    }
  }
  gbar(barCnt, 2);

  // ===== S3: interlayer x1 = elu(h1 @ Wi1 + bi1), 32-row tiles.
  for (int t = bid; t < NADJ * (NN / 32); t += NB) {
    const int g = t / (NN / 32);
    const int tile = t % (NN / 32);
    gemm_dev<NHEADS * NHID1, NHID1, 2, 1, 0, 0>(
        h1 + (size_t)g * NN * (NHEADS * NHID1), Wi1, bi1,
        x1 + (size_t)g * NN * NHID1, nullptr, nullptr, nullptr, tile * 32,
        smem, smem + 32 * 36);
  }
  gbar(barCnt, 3);

  // ===== S4: L2 GAT GEMM Wh2 = x1 @ W2 (+coef2, bf16), 128-row tiles.
  for (int t = bid; t < NADJ * NHEADS * (NN / 128); t += NB) {
    const int tile = t % (NN / 128);
    const int h = (t / (NN / 128)) % NHEADS;
    const int g = t / ((NN / 128) * NHEADS);
    const int gh = g * NHEADS + h;
    gemm_dev<NHID1, NHID2, 4, 0, 1, 1>(
        x1 + (size_t)g * NN * NHID1, W2 + (size_t)gh * NHID1 * NHID2, nullptr,
        Wh2 + (size_t)gh * NN * NHID2, a2 + (size_t)gh * 2 * NHID2,
        fs2 + (size_t)gh * NN, fd2 + (size_t)gh * NN, tile * 128, smem,
        smem + 32 * 132);
  }
  gbar(barCnt, 4);

  // ===== S5: L2 aggregate — one (g,h,n) per wave, 8 tasks/wave.
  {
    float* wgtrow = smem + wave * CAP;
    int* midxrow = (int*)(smem + 4 * CAP) + wave * CAP;
    const int gw = bid * 4 + wave;
    for (int tsk = gw; tsk < NADJ * NHEADS * NN; tsk += NB * 4) {
      const int n = tsk & (NN - 1);
      const int h = (tsk >> 12) & (NHEADS - 1);
      const int g = tsk >> 14;
      agg_task<NHID2>(g, h, n, Wh2, fs2, fd2, eidx, ecnt, h2, lane, wgtrow, midxrow);
    }
  }
  gbar(barCnt, 5);

  // ===== S6: tail — o2 = elu(h2@Wi2+bi2), logits=cat@Wf+bf, log_softmax, l1.
  for (int t = bid; t < NN / 16; t += NB) {
    constexpr int K = NHEADS * NHID2;  // 128
    float* A0 = smem;                  // [16][K+4]
    float* A1 = smem + 16 * (K + 4);
    float* Bs = A1 + 16 * (K + 4);     // [K][8]
    float* WfS = Bs + K * NCLASS;      // [16][8]
    float* cat = WfS + 16 * NCLASS;    // [16][17]
    const int row0 = t * 16;
    __syncthreads();
    for (int i = tid; i < 16 * (K / 4); i += 256) {
      const int r = i >> 5, e = i & 31;
      *(float4*)&A0[r * (K + 4) + e * 4] =
          *(const float4*)(h2 + (size_t)(row0 + r) * K + e * 4);
      *(float4*)&A1[r * (K + 4) + e * 4] =
          *(const float4*)(h2 + (size_t)NN * K + (size_t)(row0 + r) * K + e * 4);
    }
    ((float4*)Bs)[tid] = ((const float4*)Wi2)[tid];
    if (tid < 32) ((float4*)WfS)[tid] = ((const float4*)Wf)[tid];
    __syncthreads();
    const int c = tid & 7;
    const int kk = (tid >> 3) & 1;
    const int r = tid >> 4;
    float s0 = kk ? 0.f : bi2[c], s1 = kk ? 0.f : bi2[c];
#pragma unroll 8
    for (int k = kk * (K / 2); k < (kk + 1) * (K / 2); ++k) {
      s0 += A0[r * (K + 4) + k] * Bs[k * NCLASS + c];
      s1 += A1[r * (K + 4) + k] * Bs[k * NCLASS + c];
    }
    s0 += __shfl_xor(s0, 8);
    s1 += __shfl_xor(s1, 8);
    if (kk == 0) {
      cat[r * 17 + c] = s0 > 0.f ? s0 : (__expf(s0) - 1.f);
      cat[r * 17 + NCLASS + c] = s1 > 0.f ? s1 : (__expf(s1) - 1.f);
    }
    __syncthreads();
    float logit = bfv[c];
#pragma unroll
    for (int k = 0; k < 2 * NCLASS; ++k) logit += cat[r * 17 + k] * WfS[k * NCLASS + c];
    float m = logit;
#pragma unroll
    for (int off = 4; off; off >>= 1) m = fmaxf(m, __shfl_xor(m, off));
    float s = __expf(logit - m);
#pragma unroll
    for (int off = 4; off; off >>= 1) s += __shfl_xor(s, off);
    if (kk == 0) out[(size_t)(row0 + r) * NCLASS + c] = logit - (logf(s) + m);
    if (t == 0 && tid < 64) {
      float v = fabsf(Wf[tid]) + fabsf(Wf[64 + tid]);
      for (int off = 32; off; off >>= 1) v += __shfl_xor(v, off);
      if (tid == 0) out[NN * NCLASS] = v * (1.f / (2 * NCLASS * NCLASS));
    }
  }
}

// ---------------------------------------------------------------------------
extern "C" void kernel_launch(void* const* d_in, const int* in_sizes, int n_in,
                              void* d_out, int out_size, void* d_ws, size_t ws_size,
                              hipStream_t stream) {
  const float* x = (const float*)d_in[0];
  const float* adj = (const float*)d_in[1];
  const float* W1 = (const float*)d_in[2];
  const float* a1 = (const float*)d_in[3];
  const float* W2 = (const float*)d_in[4];
  const float* a2 = (const float*)d_in[5];
  const float* Wi1 = (const float*)d_in[6];
  const float* bi1 = (const float*)d_in[7];
  const float* Wi2 = (const float*)d_in[8];
  const float* bi2 = (const float*)d_in[9];
  const float* Wf = (const float*)d_in[10];
  const float* bfv = (const float*)d_in[11];
  float* out = (float*)d_out;

  char* ws = (char*)d_ws;
  int* barCnt = (int*)ws;
  ws += 256;
  int* eidx = (int*)ws;            ws += (size_t)NADJ * NN * CAP * 4;            // 4 MB
  int* ecnt = (int*)ws;            ws += (size_t)NADJ * NN * 4;
  unsigned short* Wh1 = (unsigned short*)ws;
  ws += (size_t)NADJ * NHEADS * NN * NHID1 * 2;                                   // 4 MB
  float* fs1 = (float*)ws;         ws += (size_t)NADJ * NHEADS * NN * 4;
  float* fd1 = (float*)ws;         ws += (size_t)NADJ * NHEADS * NN * 4;
  float* h1 = (float*)ws;          ws += (size_t)NADJ * NN * NHEADS * NHID1 * 4;  // 8 MB
  float* x1 = (float*)ws;          ws += (size_t)NADJ * NN * NHID1 * 4;           // 2 MB
  unsigned short* Wh2 = (unsigned short*)ws;
  ws += (size_t)NADJ * NHEADS * NN * NHID2 * 2;                                   // 2 MB
  float* fs2 = (float*)ws;         ws += (size_t)NADJ * NHEADS * NN * 4;
  float* fd2 = (float*)ws;         ws += (size_t)NADJ * NHEADS * NN * 4;
  float* h2 = (float*)ws;          ws += (size_t)NADJ * NN * NHEADS * NHID2 * 4;  // 4 MB

  // Reset device-barrier counter (capture-legal async memset), then one launch.
  hipMemsetAsync(d_ws, 0, 256, stream);
  mega<<<NB, 256, 0, stream>>>(x, adj, W1, a1, W2, a2, Wi1, bi1, Wi2, bi2, Wf,
                               bfv, out, barCnt, eidx, ecnt, Wh1, fs1, fd1, h1,
                               x1, Wh2, fs2, fd2, h2);
}

// Round 17
// 100.812 us; speedup vs baseline: 1199.4778x; 1199.4778x over previous
//
#include <hip/hip_runtime.h>
#include <hip/hip_bf16.h>

#define NN 4096
#define NFEAT 256
#define NHID1 64
#define NHID2 32
#define NCLASS 8
#define NHEADS 4
#define NADJ 2
#define CAP 128

// f32 -> bf16 with round-to-nearest-even (bit trick, no lib dependence)
__device__ __forceinline__ unsigned short f2bf(float v) {
  unsigned int x = __float_as_uint(v);
  return (unsigned short)((x + 0x7fffu + ((x >> 16) & 1u)) >> 16);
}

// ---------------------------------------------------------------------------
// Register-blocked tiled GEMM body: C = act(A @ B + bias); optional fused
// attention coefs from the f32 accumulators; optional bf16 output.
template <int KDIM, int NDIM, int RPTY, int ACT, int COEF, int OBF16>
__device__ __forceinline__ void gemm_body(
    const float* __restrict__ A, const float* __restrict__ B,
    const float* __restrict__ bias, void* __restrict__ C,
    const float* __restrict__ ag, float* __restrict__ fsrc,
    float* __restrict__ fdst, const int row0b,
    float* __restrict__ sA, float* __restrict__ sB) {
  constexpr int KT = 32;
  constexpr int TX = NDIM / 4;
  constexpr int TY = 256 / TX;
  constexpr int BR = TY * RPTY;
  constexpr int LDA = BR + 4;
  constexpr int LDB = NDIM + 4;
  const int tid = threadIdx.x;
  const int tx = tid % TX, ty = tid / TX;
  const int c0 = tx * 4;
  float acc[RPTY][4];
#pragma unroll
  for (int i = 0; i < RPTY; ++i)
#pragma unroll
    for (int j = 0; j < 4; ++j) acc[i][j] = 0.f;

  for (int kt = 0; kt < KDIM; kt += KT) {
    __syncthreads();
    for (int i = tid; i < BR * (KT / 4); i += 256) {
      const int r = i / (KT / 4), e = i % (KT / 4);
      const float4 v = *(const float4*)(A + (size_t)(row0b + r) * KDIM + kt + e * 4);
      sA[(e * 4 + 0) * LDA + r] = v.x;
      sA[(e * 4 + 1) * LDA + r] = v.y;
      sA[(e * 4 + 2) * LDA + r] = v.z;
      sA[(e * 4 + 3) * LDA + r] = v.w;
    }
    for (int i = tid; i < KT * (NDIM / 4); i += 256) {
      const int k = i / (NDIM / 4), cc = i % (NDIM / 4);
      *(float4*)&sB[k * LDB + cc * 4] = *(const float4*)(B + (size_t)(kt + k) * NDIM + cc * 4);
    }
    __syncthreads();
#pragma unroll
    for (int k = 0; k < KT; ++k) {
      float a4[RPTY];
      if constexpr (RPTY == 4) {
        const float4 t = *(const float4*)&sA[k * LDA + ty * 4];
        a4[0] = t.x; a4[1] = t.y; a4[2] = t.z; a4[3] = t.w;
      } else {
        const float2 t = *(const float2*)&sA[k * LDA + ty * 2];
        a4[0] = t.x; a4[1] = t.y;
      }
      const float4 bv = *(const float4*)&sB[k * LDB + c0];
      const float b4[4] = {bv.x, bv.y, bv.z, bv.w};
#pragma unroll
      for (int i = 0; i < RPTY; ++i)
#pragma unroll
        for (int j = 0; j < 4; ++j) acc[i][j] += a4[i] * b4[j];
    }
  }
  float b4[4] = {0.f, 0.f, 0.f, 0.f};
  if (bias) {
    const float4 bb = *(const float4*)&bias[c0];
    b4[0] = bb.x; b4[1] = bb.y; b4[2] = bb.z; b4[3] = bb.w;
  }
#pragma unroll
  for (int i = 0; i < RPTY; ++i) {
    const int row = row0b + ty * RPTY + i;
    float v[4];
#pragma unroll
    for (int j = 0; j < 4; ++j) {
      v[j] = acc[i][j] + b4[j];
      if (ACT == 1) v[j] = v[j] > 0.f ? v[j] : (__expf(v[j]) - 1.f);  // elu
    }
    if constexpr (OBF16) {
      ushort4 o;
      o.x = f2bf(v[0]); o.y = f2bf(v[1]); o.z = f2bf(v[2]); o.w = f2bf(v[3]);
      *(ushort4*)((unsigned short*)C + (size_t)row * NDIM + c0) = o;
    } else {
      float4 o;
      o.x = v[0]; o.y = v[1]; o.z = v[2]; o.w = v[3];
      *(float4*)((float*)C + (size_t)row * NDIM + c0) = o;
    }
  }
  if constexpr (COEF) {
    float aS[4], aD[4];
#pragma unroll
    for (int j = 0; j < 4; ++j) { aS[j] = ag[c0 + j]; aD[j] = ag[NDIM + c0 + j]; }
#pragma unroll
    for (int i = 0; i < RPTY; ++i) {
      float s = 0.f, d = 0.f;
#pragma unroll
      for (int j = 0; j < 4; ++j) { s += acc[i][j] * aS[j]; d += acc[i][j] * aD[j]; }
#pragma unroll
      for (int off = TX / 2; off; off >>= 1) {
        s += __shfl_xor(s, off);
        d += __shfl_xor(d, off);
      }
      if (tx == 0) {
        const int row = row0b + ty * RPTY + i;
        fsrc[row] = s;
        fdst[row] = d;
      }
    }
  }
}

// ---------------------------------------------------------------------------
// K1: blocks [0,512) = L1 GAT GEMM (+coef1, bf16 Wh1); rest = edge build.
__global__ __launch_bounds__(256) void k1_gemm_edges(
    const float* __restrict__ x, const float* __restrict__ W1,
    const float* __restrict__ a1, unsigned short* __restrict__ Wh1,
    float* __restrict__ fs1, float* __restrict__ fd1,
    const float* __restrict__ adj, int* __restrict__ eidx,
    int* __restrict__ ecnt) {
  __shared__ float sA[32 * (64 + 4)];
  __shared__ float sB[32 * (64 + 4)];
  constexpr int NB_GEMM = (NN / 64) * NHEADS * NADJ;  // 512
  if (blockIdx.x < NB_GEMM) {
    int b = blockIdx.x;
    const int tile = b % (NN / 64); b /= (NN / 64);
    const int h = b % NHEADS;
    const int g = b / NHEADS;
    const int gh = g * NHEADS + h;
    gemm_body<NFEAT, NHID1, 4, 0, 1, 1>(
        x, W1 + (size_t)gh * NFEAT * NHID1, nullptr,
        Wh1 + (size_t)gh * NN * NHID1, a1 + (size_t)gh * 2 * NHID1,
        fs1 + (size_t)gh * NN, fd1 + (size_t)gh * NN, tile * 64, sA, sB);
  } else {
    const int wave = threadIdx.x >> 6;
    const int lane = threadIdx.x & 63;
    const int r = (blockIdx.x - NB_GEMM) * 4 + wave;  // g*NN + n
    const float4* row = (const float4*)(adj + (size_t)r * NN);
    int* out = eidx + (size_t)r * CAP;
    int base = 0;
    for (int c = 0; c < NN; c += 256) {
      const float4 v = row[(c >> 2) + lane];
      const int j0 = c + lane * 4;
      const float vt[4] = {v.x, v.y, v.z, v.w};
#pragma unroll
      for (int t = 0; t < 4; ++t) {
        const bool hit = vt[t] > 0.f;
        const unsigned long long m = __ballot(hit);
        if (hit) {
          const int pos = base + __popcll(m & ((1ull << lane) - 1ull));
          if (pos < CAP) out[pos] = j0 + t;
        }
        base += __popcll(m);
      }
    }
    if (lane == 0) ecnt[r] = base < CAP ? base : CAP;
  }
}

// ---------------------------------------------------------------------------
// Standalone GEMM wrapper.
template <int KDIM, int NDIM, int RPTY, int ACT, int COEF, int OBF16>
__global__ __launch_bounds__(256) void gemm_tile(
    const float* __restrict__ A, const float* __restrict__ B,
    const float* __restrict__ bias, void* __restrict__ C,
    const float* __restrict__ av, float* __restrict__ fsrc,
    float* __restrict__ fdst,
    size_t asG, size_t bsH, size_t bsG, size_t csH, size_t csG) {
  constexpr int TX = NDIM / 4;
  constexpr int TY = 256 / TX;
  constexpr int BR = TY * RPTY;
  __shared__ float sA[32 * (BR + 4)];
  __shared__ float sB[32 * (NDIM + 4)];
  const int g = blockIdx.z, h = blockIdx.y;
  const int gh = g * NHEADS + h;
  void* Cp;
  if constexpr (OBF16)
    Cp = (void*)((unsigned short*)C + (size_t)g * csG + (size_t)h * csH);
  else
    Cp = (void*)((float*)C + (size_t)g * csG + (size_t)h * csH);
  gemm_body<KDIM, NDIM, RPTY, ACT, COEF, OBF16>(
      A + (size_t)g * asG, B + (size_t)g * bsG + (size_t)h * bsH, bias, Cp,
      COEF ? av + (size_t)gh * 2 * NDIM : nullptr,
      COEF ? fsrc + (size_t)gh * NN : nullptr,
      COEF ? fdst + (size_t)gh * NN : nullptr,
      (int)blockIdx.x * BR, sA, sB);
}

// ---------------------------------------------------------------------------
// Sparse masked softmax + aggregation + ELU, one (n,h,g) per wave.
// Gather reads bf16 Wh: each lane loads uint4 = 8 bf16 channels (16B);
// CPL = O/8 lanes per edge row, EPW = 64/CPL edges in parallel, x2 unroll.
#define GATB(ACC, JJ)                                                          \
  {                                                                            \
    const float w_ = wgt[wave][JJ];                                            \
    const uint4 v_ = *(const uint4*)(WhH + (size_t)midx[wave][JJ] * O + c8);   \
    ACC[0] += w_ * __uint_as_float(v_.x << 16);                                \
    ACC[1] += w_ * __uint_as_float(v_.x & 0xffff0000u);                        \
    ACC[2] += w_ * __uint_as_float(v_.y << 16);                                \
    ACC[3] += w_ * __uint_as_float(v_.y & 0xffff0000u);                        \
    ACC[4] += w_ * __uint_as_float(v_.z << 16);                                \
    ACC[5] += w_ * __uint_as_float(v_.z & 0xffff0000u);                        \
    ACC[6] += w_ * __uint_as_float(v_.w << 16);                                \
    ACC[7] += w_ * __uint_as_float(v_.w & 0xffff0000u);                        \
  }

template <int O>
__global__ __launch_bounds__(256) void aggregate(
    const unsigned short* __restrict__ Wh, const float* __restrict__ fsrc,
    const float* __restrict__ fdst, const int* __restrict__ eidx,
    const int* __restrict__ ecnt, float* __restrict__ Hout) {
  constexpr int CPL = O / 8;     // lanes per edge row
  constexpr int EPW = 64 / CPL;  // edges in parallel
  __shared__ float wgt[4][CAP];
  __shared__ int midx[4][CAP];
  const int wave = threadIdx.x >> 6;
  const int lane = threadIdx.x & 63;
  const int n = blockIdx.x * 4 + wave;
  const int h = blockIdx.y, g = blockIdx.z;
  const int gh = g * NHEADS + h;
  const int cnt = ecnt[(size_t)g * NN + n];
  const int* ei = eidx + (size_t)(g * NN + n) * CAP;
  const float fs = fsrc[(size_t)gh * NN + n];
  const float* fd = fdst + (size_t)gh * NN;
  float mx = -3.4e38f;
  for (int j = lane; j < cnt; j += 64) {
    const int m = ei[j];
    float e = fs + fd[m];
    e = e > 0.f ? e : 0.2f * e;  // leaky relu, alpha = 0.2
    midx[wave][j] = m;
    wgt[wave][j] = e;
    mx = fmaxf(mx, e);
  }
  for (int off = 32; off; off >>= 1) mx = fmaxf(mx, __shfl_xor(mx, off));
  float sm = 0.f;
  for (int j = lane; j < cnt; j += 64) {
    const float w = __expf(wgt[wave][j] - mx);
    wgt[wave][j] = w;
    sm += w;
  }
  for (int off = 32; off; off >>= 1) sm += __shfl_xor(sm, off);
  // gather
  const unsigned short* WhH = Wh + (size_t)gh * NN * O;
  const int sub = lane / CPL;
  const int c8 = (lane % CPL) * 8;
  float A0[8] = {0, 0, 0, 0, 0, 0, 0, 0};
  float A1[8] = {0, 0, 0, 0, 0, 0, 0, 0};
  int j = sub;
  for (; j + EPW < cnt; j += 2 * EPW) {
    GATB(A0, j);
    GATB(A1, j + EPW);
  }
  for (; j < cnt; j += EPW) GATB(A0, j);
#pragma unroll
  for (int q = 0; q < 8; ++q) A0[q] += A1[q];
#pragma unroll
  for (int off = CPL; off < 64; off <<= 1)
#pragma unroll
    for (int q = 0; q < 8; ++q) A0[q] += __shfl_xor(A0[q], off);
  if (lane < CPL) {
    const float inv = 1.f / sm;
    float o[8];
#pragma unroll
    for (int q = 0; q < 8; ++q) {
      o[q] = A0[q] * inv;
      o[q] = o[q] > 0.f ? o[q] : (__expf(o[q]) - 1.f);  // elu
    }
    float* dst = Hout + (size_t)g * NN * (NHEADS * O) + (size_t)n * (NHEADS * O) +
                 h * O + lane * 8;
    float4 o0, o1;
    o0.x = o[0]; o0.y = o[1]; o0.z = o[2]; o0.w = o[3];
    o1.x = o[4]; o1.y = o[5]; o1.z = o[6]; o1.w = o[7];
    *(float4*)dst = o0;
    *(float4*)(dst + 4) = o1;
  }
}

// ---------------------------------------------------------------------------
// Fused tail: o2_g = elu(h2_g @ Wi2 + bi2), logits = concat @ Wf + bf,
// log_softmax, l1 = mean|Wf|.
__global__ __launch_bounds__(256) void tail_fused(const float* __restrict__ h2,
                                                  const float* __restrict__ Wi2,
                                                  const float* __restrict__ bi2,
                                                  const float* __restrict__ Wf,
                                                  const float* __restrict__ bfv,
                                                  float* __restrict__ out) {
  constexpr int K = NHEADS * NHID2;  // 128
  __shared__ float A0[16][K + 4];
  __shared__ float A1[16][K + 4];
  __shared__ float Bs[K][NCLASS];
  __shared__ float WfS[2 * NCLASS][NCLASS];
  __shared__ float cat[16][2 * NCLASS + 1];
  const int tid = threadIdx.x;
  const int row0 = blockIdx.x * 16;
  for (int i = tid; i < 16 * (K / 4); i += 256) {
    const int r = i >> 5, e = i & 31;
    *(float4*)&A0[r][e * 4] = *(const float4*)(h2 + (size_t)(row0 + r) * K + e * 4);
    *(float4*)&A1[r][e * 4] =
        *(const float4*)(h2 + (size_t)NN * K + (size_t)(row0 + r) * K + e * 4);
  }
  ((float4*)Bs)[tid] = ((const float4*)Wi2)[tid];
  if (tid < 32) ((float4*)WfS)[tid] = ((const float4*)Wf)[tid];
  __syncthreads();
  const int c = tid & 7;
  const int kk = (tid >> 3) & 1;
  const int r = tid >> 4;
  float s0 = kk ? 0.f : bi2[c], s1 = kk ? 0.f : bi2[c];
#pragma unroll 8
  for (int k = kk * (K / 2); k < (kk + 1) * (K / 2); ++k) {
    s0 += A0[r][k] * Bs[k][c];
    s1 += A1[r][k] * Bs[k][c];
  }
  s0 += __shfl_xor(s0, 8);
  s1 += __shfl_xor(s1, 8);
  if (kk == 0) {
    cat[r][c] = s0 > 0.f ? s0 : (__expf(s0) - 1.f);
    cat[r][NCLASS + c] = s1 > 0.f ? s1 : (__expf(s1) - 1.f);
  }
  __syncthreads();
  float logit = bfv[c];
#pragma unroll
  for (int k = 0; k < 2 * NCLASS; ++k) logit += cat[r][k] * WfS[k][c];
  float m = logit;
#pragma unroll
  for (int off = 4; off; off >>= 1) m = fmaxf(m, __shfl_xor(m, off));
  float s = __expf(logit - m);
#pragma unroll
  for (int off = 4; off; off >>= 1) s += __shfl_xor(s, off);
  if (kk == 0) out[(size_t)(row0 + r) * NCLASS + c] = logit - (logf(s) + m);
  if (blockIdx.x == 0 && tid < 64) {
    float v = fabsf(Wf[tid]) + fabsf(Wf[64 + tid]);
    for (int off = 32; off; off >>= 1) v += __shfl_xor(v, off);
    if (tid == 0) out[NN * NCLASS] = v * (1.f / (2 * NCLASS * NCLASS));
  }
}

// ---------------------------------------------------------------------------
extern "C" void kernel_launch(void* const* d_in, const int* in_sizes, int n_in,
                              void* d_out, int out_size, void* d_ws, size_t ws_size,
                              hipStream_t stream) {
  const float* x = (const float*)d_in[0];
  const float* adj = (const float*)d_in[1];
  const float* W1 = (const float*)d_in[2];
  const float* a1 = (const float*)d_in[3];
  const float* W2 = (const float*)d_in[4];
  const float* a2 = (const float*)d_in[5];
  const float* Wi1 = (const float*)d_in[6];
  const float* bi1 = (const float*)d_in[7];
  const float* Wi2 = (const float*)d_in[8];
  const float* bi2 = (const float*)d_in[9];
  const float* Wf = (const float*)d_in[10];
  const float* bfv = (const float*)d_in[11];
  float* out = (float*)d_out;

  char* ws = (char*)d_ws;
  int* eidx = (int*)ws;            ws += (size_t)NADJ * NN * CAP * 4;             // 4 MB
  int* ecnt = (int*)ws;            ws += (size_t)NADJ * NN * 4;
  unsigned short* Wh1 = (unsigned short*)ws;
  ws += (size_t)NADJ * NHEADS * NN * NHID1 * 2;                                    // 4 MB
  float* fs1 = (float*)ws;         ws += (size_t)NADJ * NHEADS * NN * 4;
  float* fd1 = (float*)ws;         ws += (size_t)NADJ * NHEADS * NN * 4;
  float* h1 = (float*)ws;          ws += (size_t)NADJ * NN * NHEADS * NHID1 * 4;   // 8 MB
  float* x1 = (float*)ws;          ws += (size_t)NADJ * NN * NHID1 * 4;            // 2 MB
  unsigned short* Wh2 = (unsigned short*)ws;
  ws += (size_t)NADJ * NHEADS * NN * NHID2 * 2;                                    // 2 MB
  float* fs2 = (float*)ws;         ws += (size_t)NADJ * NHEADS * NN * 4;
  float* fd2 = (float*)ws;         ws += (size_t)NADJ * NHEADS * NN * 4;
  float* h2 = (float*)ws;          ws += (size_t)NADJ * NN * NHEADS * NHID2 * 4;   // 4 MB

  // K1: L1 GEMM (+coef1, bf16 out) overlapped with edge-list build.
  k1_gemm_edges<<<512 + NADJ * NN / 4, 256, 0, stream>>>(
      x, W1, a1, Wh1, fs1, fd1, adj, eidx, ecnt);

  // L1 aggregate (bf16 gather).
  aggregate<NHID1><<<dim3(NN / 4, NHEADS, NADJ), 256, 0, stream>>>(
      Wh1, fs1, fd1, eidx, ecnt, h1);

  // Interlayer linear + elu (f32).
  gemm_tile<NHEADS * NHID1, NHID1, 2, 1, 0, 0><<<dim3(NN / 32, 1, NADJ), 256, 0, stream>>>(
      h1, Wi1, bi1, x1, nullptr, nullptr, nullptr,
      (size_t)NN * NHEADS * NHID1, 0, 0, 0, (size_t)NN * NHID1);

  // L2 GAT GEMM (+coef2, bf16 out).
  gemm_tile<NHID1, NHID2, 4, 0, 1, 1><<<dim3(NN / 128, NHEADS, NADJ), 256, 0, stream>>>(
      x1, W2, nullptr, Wh2, a2, fs2, fd2,
      (size_t)NN * NHID1, (size_t)NHID1 * NHID2, (size_t)NHEADS * NHID1 * NHID2,
      (size_t)NN * NHID2, (size_t)NHEADS * NN * NHID2);

  // L2 aggregate (bf16 gather).
  aggregate<NHID2><<<dim3(NN / 4, NHEADS, NADJ), 256, 0, stream>>>(
      Wh2, fs2, fd2, eidx, ecnt, h2);

  tail_fused<<<NN / 16, 256, 0, stream>>>(h2, Wi2, bi2, Wf, bfv, out);
}